// Round 1
// baseline (7470.467 us; speedup 1.0000x reference)
//
#include <hip/hip_runtime.h>
#include <hip/hip_bf16.h>

#define N_NODES 16384
#define FDIM 512

// ---------------- K1: xw = x @ W1  ([N,512]@[512,16]) ----------------
// One wave per row; lanes stride k; W1 staged transposed in LDS.
__global__ __launch_bounds__(256) void k1_xw(const float* __restrict__ x,
                                             const float* __restrict__ W1,
                                             float* __restrict__ xw) {
    __shared__ float lw[16 * FDIM]; // transposed: lw[c*512 + k]
    const int tid = threadIdx.x;
#pragma unroll
    for (int s = 0; s < 8; ++s) {
        int idx = s * 1024 + tid * 4; // dword index into W1 (8192 dwords)
        float4 v = *reinterpret_cast<const float4*>(W1 + idx);
#pragma unroll
        for (int j = 0; j < 4; ++j) {
            int k = (idx + j) >> 4, c = (idx + j) & 15;
            lw[c * FDIM + k] = (&v.x)[j];
        }
    }
    __syncthreads();
    const int lane = tid & 63, w = tid >> 6;
    const size_t row = (size_t)blockIdx.x * 4 + w;

    float acc[16];
#pragma unroll
    for (int c = 0; c < 16; ++c) acc[c] = 0.f;

#pragma unroll
    for (int it = 0; it < 2; ++it) {
        const int k = it * 256 + lane * 4;
        float4 xv = *reinterpret_cast<const float4*>(x + row * FDIM + k);
#pragma unroll
        for (int c = 0; c < 16; ++c) {
            float4 wv = *reinterpret_cast<const float4*>(lw + c * FDIM + k);
            acc[c] += xv.x * wv.x + xv.y * wv.y + xv.z * wv.z + xv.w * wv.w;
        }
    }
#pragma unroll
    for (int c = 0; c < 16; ++c) {
        float s = acc[c];
        s += __shfl_xor(s, 1);  s += __shfl_xor(s, 2);  s += __shfl_xor(s, 4);
        s += __shfl_xor(s, 8);  s += __shfl_xor(s, 16); s += __shfl_xor(s, 32);
        acc[c] = s;
    }
    if (lane == 0) {
#pragma unroll
        for (int c = 0; c < 16; ++c) xw[row * 16 + c] = acc[c];
    }
}

// ---------------- K2/K4: out = [relu](A @ V + bias)  ([N,N]@[N,16]) ----------------
// The HBM-bound kernel. 8 rows/wave, lanes stride k (coalesced float4 A loads),
// V tile staged transposed in LDS ([16][KT], b128 reads at 16B lane stride).
#define KT 1024
#define RPW 8
#define RPB 32  // 4 waves * 8 rows

template <int RELU>
__global__ __launch_bounds__(256, 2) void k_agg(const float* __restrict__ A,
                                                const float* __restrict__ V,
                                                const float* __restrict__ bias,
                                                float* __restrict__ out) {
    __shared__ float lv[16 * KT]; // 64 KB, transposed: lv[c*KT + k_local]
    const int tid = threadIdx.x;
    const int lane = tid & 63;
    const int w = tid >> 6;
    const size_t row0 = (size_t)blockIdx.x * RPB + (size_t)w * RPW;

    float acc[RPW][16];
#pragma unroll
    for (int r = 0; r < RPW; ++r)
#pragma unroll
        for (int c = 0; c < 16; ++c) acc[r][c] = 0.f;

    for (int t = 0; t < N_NODES; t += KT) {
        __syncthreads();
        // stage V[t..t+KT][16] -> lv transposed (16384 dwords, 64/thread)
#pragma unroll
        for (int s = 0; s < 16; ++s) {
            int idx = s * 1024 + tid * 4;
            float4 v = *reinterpret_cast<const float4*>(V + (size_t)t * 16 + idx);
#pragma unroll
            for (int j = 0; j < 4; ++j) {
                int k = (idx + j) >> 4, c = (idx + j) & 15;
                lv[c * KT + k] = (&v.x)[j];
            }
        }
        __syncthreads();

#pragma unroll
        for (int it = 0; it < KT / 256; ++it) {
            const int kl = it * 256 + lane * 4;
            float4 a[RPW];
#pragma unroll
            for (int r = 0; r < RPW; ++r)
                a[r] = *reinterpret_cast<const float4*>(
                    A + (row0 + r) * (size_t)N_NODES + (size_t)t + kl);
#pragma unroll
            for (int c = 0; c < 16; ++c) {
                float4 v = *reinterpret_cast<const float4*>(lv + c * KT + kl);
#pragma unroll
                for (int r = 0; r < RPW; ++r)
                    acc[r][c] += a[r].x * v.x + a[r].y * v.y + a[r].z * v.z + a[r].w * v.w;
            }
        }
    }

    // butterfly-reduce all 128 (r,c) partials across the wave; lane v=r*16+c
    // keeps value v (and v+64) -> coalesced 128-dword store per wave.
    float o0 = 0.f, o1 = 0.f;
#pragma unroll
    for (int r = 0; r < RPW; ++r) {
#pragma unroll
        for (int c = 0; c < 16; ++c) {
            float s = acc[r][c];
            s += __shfl_xor(s, 1);  s += __shfl_xor(s, 2);  s += __shfl_xor(s, 4);
            s += __shfl_xor(s, 8);  s += __shfl_xor(s, 16); s += __shfl_xor(s, 32);
            const int v = r * 16 + c;
            o0 = (v == lane) ? s : o0;
            o1 = (v == lane + 64) ? s : o1;
        }
    }
    const float b = bias[lane & 15];
    o0 += b; o1 += b;
    if (RELU) { o0 = fmaxf(o0, 0.f); o1 = fmaxf(o1, 0.f); }
    const size_t base = row0 * 16;
    out[base + lane] = o0;
    out[base + 64 + lane] = o1;
}

// ---------------- K3: hw = h1 @ W2  ([N,16]@[16,16]) ----------------
__global__ __launch_bounds__(256) void k3_hw(const float* __restrict__ h1,
                                             const float* __restrict__ W2,
                                             float* __restrict__ hw) {
    __shared__ float w2s[256];
    w2s[threadIdx.x] = W2[threadIdx.x];
    __syncthreads();
    const size_t r = (size_t)blockIdx.x * 256 + threadIdx.x;
    float h[16];
#pragma unroll
    for (int q = 0; q < 4; ++q) {
        float4 v = *reinterpret_cast<const float4*>(h1 + r * 16 + q * 4);
        h[q * 4 + 0] = v.x; h[q * 4 + 1] = v.y; h[q * 4 + 2] = v.z; h[q * 4 + 3] = v.w;
    }
#pragma unroll
    for (int q = 0; q < 4; ++q) {
        float4 o;
#pragma unroll
        for (int j = 0; j < 4; ++j) {
            const int c = q * 4 + j;
            float s = 0.f;
#pragma unroll
            for (int k = 0; k < 16; ++k) s += h[k] * w2s[k * 16 + c];
            (&o.x)[j] = s;
        }
        *reinterpret_cast<float4*>(hw + r * 16 + q * 4) = o;
    }
}

// ---------------- K5: out = softmax(g) @ Wd + bd ----------------
__global__ __launch_bounds__(256) void k5_head(const float* __restrict__ g,
                                               const float* __restrict__ Wd,
                                               const float* __restrict__ bd,
                                               float* __restrict__ out) {
    const size_t r = (size_t)blockIdx.x * 256 + threadIdx.x;
    float v[16];
#pragma unroll
    for (int q = 0; q < 4; ++q) {
        float4 t = *reinterpret_cast<const float4*>(g + r * 16 + q * 4);
        v[q * 4 + 0] = t.x; v[q * 4 + 1] = t.y; v[q * 4 + 2] = t.z; v[q * 4 + 3] = t.w;
    }
    float m = v[0];
#pragma unroll
    for (int c = 1; c < 16; ++c) m = fmaxf(m, v[c]);
    float se = 0.f, sd = 0.f;
#pragma unroll
    for (int c = 0; c < 16; ++c) {
        const float e = expf(v[c] - m);
        se += e;
        sd += e * Wd[c];
    }
    out[r] = sd / se + bd[0];
}

extern "C" void kernel_launch(void* const* d_in, const int* in_sizes, int n_in,
                              void* d_out, int out_size, void* d_ws, size_t ws_size,
                              hipStream_t stream) {
    const float* x  = (const float*)d_in[0];
    const float* A  = (const float*)d_in[1];
    const float* W1 = (const float*)d_in[2];
    const float* b1 = (const float*)d_in[3];
    const float* W2 = (const float*)d_in[4];
    const float* b2 = (const float*)d_in[5];
    const float* Wd = (const float*)d_in[6];
    const float* bd = (const float*)d_in[7];
    float* out = (float*)d_out;

    float* ws = (float*)d_ws;
    float* xw = ws;                        // [N,16] 1 MB
    float* h1 = ws + 1 * N_NODES * 16;     // [N,16] 1 MB
    float* hw = ws + 2 * N_NODES * 16;     // [N,16] 1 MB
    float* gl = ws + 3 * N_NODES * 16;     // [N,16] 1 MB

    k1_xw<<<N_NODES / 4, 256, 0, stream>>>(x, W1, xw);
    k_agg<1><<<N_NODES / RPB, 256, 0, stream>>>(A, xw, b1, h1);
    k3_hw<<<N_NODES / 256, 256, 0, stream>>>(h1, W2, hw);
    k_agg<0><<<N_NODES / RPB, 256, 0, stream>>>(A, hw, b2, gl);
    k5_head<<<N_NODES / 256, 256, 0, stream>>>(gl, Wd, bd, out);
}

// Round 2
// 2275.924 us; speedup vs baseline: 3.2824x; 3.2824x over previous
//
#include <hip/hip_runtime.h>
#include <hip/hip_bf16.h>

#define N_NODES 16384
#define FDIM 512

// ---------------- row-aggregation GEMM: out = [relu](A @ V [+ bias]) ----------------
// A: [N, KTOT] fp32, V: [KTOT, 16] fp32, out: [N, 16].
// Structure: 256 threads = 4 waves; each wave owns 4 rows; lanes stride k with
// float4 loads of A (1 KB/wave/instr, coalesced). V staged per 512-k tile into
// LDS transposed [16][512+4] (pad -> conflict-free b128 reads, 2-way writes).
// acc[4][16] = 64 VGPRs -> no spill (the round-1 killer).
template <int KTOT, int RELU, int HASBIAS>
__global__ __launch_bounds__(256, 3) void k_rowagg(const float* __restrict__ A,
                                                   const float* __restrict__ V,
                                                   const float* __restrict__ bias,
                                                   float* __restrict__ out) {
    constexpr int KT = 512;
    constexpr int LVS = KT + 4; // pad: staging writes 2-way (free), reads conflict-free
    __shared__ float lv[16 * LVS]; // ~33 KB -> 4 blocks/CU
    const int tid = threadIdx.x;
    const int lane = tid & 63;
    const int w = tid >> 6;
    const size_t row0 = (size_t)blockIdx.x * 16 + (size_t)w * 4;

    float acc[4][16];
#pragma unroll
    for (int r = 0; r < 4; ++r)
#pragma unroll
        for (int c = 0; c < 16; ++c) acc[r][c] = 0.f;

    for (int t = 0; t < KTOT; t += KT) {
        __syncthreads();
        // stage V[t..t+KT][16] -> lv transposed (8192 dwords, 32/thread)
#pragma unroll
        for (int s = 0; s < 8; ++s) {
            const int idx = s * 1024 + tid * 4; // idx%16 in {0,4,8,12}: one k, 4 c's
            const float4 v = *reinterpret_cast<const float4*>(V + (size_t)t * 16 + idx);
            const int k = idx >> 4;
            const int c0 = idx & 15;
            lv[(c0 + 0) * LVS + k] = v.x;
            lv[(c0 + 1) * LVS + k] = v.y;
            lv[(c0 + 2) * LVS + k] = v.z;
            lv[(c0 + 3) * LVS + k] = v.w;
        }
        __syncthreads();

#pragma unroll
        for (int it = 0; it < KT / 256; ++it) {
            const int kl = it * 256 + lane * 4;
            float4 a[4];
#pragma unroll
            for (int r = 0; r < 4; ++r)
                a[r] = *reinterpret_cast<const float4*>(
                    A + (row0 + r) * (size_t)KTOT + (size_t)t + kl);
#pragma unroll
            for (int c = 0; c < 16; ++c) {
                const float4 v = *reinterpret_cast<const float4*>(lv + c * LVS + kl);
#pragma unroll
                for (int r = 0; r < 4; ++r)
                    acc[r][c] += a[r].x * v.x + a[r].y * v.y + a[r].z * v.z + a[r].w * v.w;
            }
        }
    }

    // butterfly-reduce the 64 (r,c) partials across the wave; lane v=r*16+c keeps
    // value v -> one coalesced 256-dword store per block.
    float o = 0.f;
#pragma unroll
    for (int r = 0; r < 4; ++r) {
#pragma unroll
        for (int c = 0; c < 16; ++c) {
            float s = acc[r][c];
            s += __shfl_xor(s, 1);  s += __shfl_xor(s, 2);  s += __shfl_xor(s, 4);
            s += __shfl_xor(s, 8);  s += __shfl_xor(s, 16); s += __shfl_xor(s, 32);
            o = (r * 16 + c == lane) ? s : o;
        }
    }
    if (HASBIAS) o += bias[lane & 15];
    if (RELU) o = fmaxf(o, 0.f);
    out[row0 * 16 + lane] = o;
}

// ---------------- K3: hw = h1 @ W2  ([N,16]@[16,16]) ----------------
__global__ __launch_bounds__(256) void k3_hw(const float* __restrict__ h1,
                                             const float* __restrict__ W2,
                                             float* __restrict__ hw) {
    __shared__ float w2s[256];
    w2s[threadIdx.x] = W2[threadIdx.x];
    __syncthreads();
    const size_t r = (size_t)blockIdx.x * 256 + threadIdx.x;
    float h[16];
#pragma unroll
    for (int q = 0; q < 4; ++q) {
        float4 v = *reinterpret_cast<const float4*>(h1 + r * 16 + q * 4);
        h[q * 4 + 0] = v.x; h[q * 4 + 1] = v.y; h[q * 4 + 2] = v.z; h[q * 4 + 3] = v.w;
    }
#pragma unroll
    for (int q = 0; q < 4; ++q) {
        float4 o;
#pragma unroll
        for (int j = 0; j < 4; ++j) {
            const int c = q * 4 + j;
            float s = 0.f;
#pragma unroll
            for (int k = 0; k < 16; ++k) s += h[k] * w2s[k * 16 + c];
            (&o.x)[j] = s;
        }
        *reinterpret_cast<float4*>(hw + r * 16 + q * 4) = o;
    }
}

// ---------------- K5: out = softmax(g) @ Wd + bd ----------------
__global__ __launch_bounds__(256) void k5_head(const float* __restrict__ g,
                                               const float* __restrict__ Wd,
                                               const float* __restrict__ bd,
                                               float* __restrict__ out) {
    const size_t r = (size_t)blockIdx.x * 256 + threadIdx.x;
    float v[16];
#pragma unroll
    for (int q = 0; q < 4; ++q) {
        float4 t = *reinterpret_cast<const float4*>(g + r * 16 + q * 4);
        v[q * 4 + 0] = t.x; v[q * 4 + 1] = t.y; v[q * 4 + 2] = t.z; v[q * 4 + 3] = t.w;
    }
    float m = v[0];
#pragma unroll
    for (int c = 1; c < 16; ++c) m = fmaxf(m, v[c]);
    float se = 0.f, sd = 0.f;
#pragma unroll
    for (int c = 0; c < 16; ++c) {
        const float e = expf(v[c] - m);
        se += e;
        sd += e * Wd[c];
    }
    out[r] = sd / se + bd[0];
}

extern "C" void kernel_launch(void* const* d_in, const int* in_sizes, int n_in,
                              void* d_out, int out_size, void* d_ws, size_t ws_size,
                              hipStream_t stream) {
    const float* x  = (const float*)d_in[0];
    const float* A  = (const float*)d_in[1];
    const float* W1 = (const float*)d_in[2];
    const float* b1 = (const float*)d_in[3];
    const float* W2 = (const float*)d_in[4];
    const float* b2 = (const float*)d_in[5];
    const float* Wd = (const float*)d_in[6];
    const float* bd = (const float*)d_in[7];
    float* out = (float*)d_out;

    float* ws = (float*)d_ws;
    float* xw = ws;                        // [N,16] 1 MB
    float* h1 = ws + 1 * N_NODES * 16;     // [N,16] 1 MB
    float* hw = ws + 2 * N_NODES * 16;     // [N,16] 1 MB
    float* gl = ws + 3 * N_NODES * 16;     // [N,16] 1 MB

    // xw = x @ W1   (KTOT=512, no bias, no relu)
    k_rowagg<FDIM, 0, 0><<<N_NODES / 16, 256, 0, stream>>>(x, W1, b1, xw);
    // h1 = relu(A @ xw + b1)
    k_rowagg<N_NODES, 1, 1><<<N_NODES / 16, 256, 0, stream>>>(A, xw, b1, h1);
    // hw = h1 @ W2
    k3_hw<<<N_NODES / 256, 256, 0, stream>>>(h1, W2, hw);
    // gl = A @ hw + b2
    k_rowagg<N_NODES, 0, 1><<<N_NODES / 16, 256, 0, stream>>>(A, hw, b2, gl);
    // out = softmax(gl) @ Wd + bd
    k5_head<<<N_NODES / 256, 256, 0, stream>>>(gl, Wd, bd, out);
}